// Round 22
// baseline (2609.632 us; speedup 1.0000x reference)
//
#include <hip/hip_runtime.h>
#include <cstdint>
#include <cstddef>

#define Bb 8
#define Nn 8192
#define Cc 64
#define NPOINT 2048
#define NSAMPLE 32
#define CIN 67      // C + 3
#define D1 64
#define D2 128
#define QGAP 624
#define ULP_WIN 4u
#define FPST 1024
#define NPTS 8      // Nn / FPST

// 64-lane u32 max via DPP (verified R21); uniform via readlane 63.
__device__ __forceinline__ unsigned int wave_umax_dpp(unsigned int v) {
#define USTEP(CTRL) { \
    unsigned int o = (unsigned int)__builtin_amdgcn_update_dpp(0, (int)v, CTRL, 0xf, 0xf, true); \
    v = (v > o) ? v : o; }
    USTEP(0x111)  // row_shr:1
    USTEP(0x112)  // row_shr:2
    USTEP(0x114)  // row_shr:4
    USTEP(0x118)  // row_shr:8
    USTEP(0x142)  // row_bcast:15
    USTEP(0x143)  // row_bcast:31
#undef USTEP
    return (unsigned int)__builtin_amdgcn_readlane((int)v, 63);
}

// XOR bank-swizzle at float4 granularity: vec-slot v -> v ^ ((v>>3)&7).
// Bijective (involution within 64-vec tiles); spreads a wave's 128
// consecutive vec-slots across all 8 bank groups (16-way -> 2-way, free).
__device__ __forceinline__ int swz_vec(int v) { return v ^ ((v >> 3) & 7); }
__device__ __forceinline__ int swz_elem(int e) {
    return (swz_vec(e >> 2) << 2) | (e & 3);
}

// ---------------------------------------------------------------------------
// FPS == R21 (passing, 2218us fps) with ONE lever: the dist-mirror float4
// writes/reads go through the XOR bank-swizzle above, killing the 16-way
// bank conflict (SQ_LDS_BANK_CONFLICT 4.19M -> ~0). Value path, reduce,
// probe semantics bit-identical to R21.
// ---------------------------------------------------------------------------
__global__ __launch_bounds__(FPST) void fps_kernel(
    const float* __restrict__ xyz,      // (B,N,3)
    float* __restrict__ out_xyz,        // (B,NPOINT,3)
    float* __restrict__ out_idx_f)      // (B,NPOINT) float view of output 2
{
    const int b = blockIdx.x;
    const float* xb = xyz + (size_t)b * Nn * 3;
    const int tid = threadIdx.x;

    float px[NPTS], py[NPTS], pz[NPTS], dist[NPTS];
#pragma unroll
    for (int j = 0; j < NPTS; ++j) {
        int p = tid * NPTS + j;
        px[j] = xb[p * 3 + 0];
        py[j] = xb[p * 3 + 1];
        pz[j] = xb[p * 3 + 2];
        dist[j] = 1e10f;
    }

    __shared__ __align__(16) float sdist[2][Nn];   // 64 KB dist mirror (parity)
    __shared__ unsigned long long skey[2][16];     // wave (dist,~idx) keys

    // precomputed swizzled vec-slots for this thread's two float4 writes
    const int pv0 = swz_vec(tid * 2);
    const int pv1 = swz_vec(tid * 2 + 1);

    float lx = xb[0], ly = xb[1], lz = xb[2];
    int win = 0;

    // register-buffered results: thread t owns iterations t and t+1024
    float r0i = 0.0f, r0x = lx, r0y = ly, r0z = lz;   // valid for t=0 (it=0)
    float r1i = 0.0f, r1x = 0.0f, r1y = 0.0f, r1z = 0.0f;

    for (int it = 1; it < NPOINT; ++it) {
        const int s = it & 1;

        float best = -1.0f;
        int bj = 0;
#pragma unroll
        for (int j = 0; j < NPTS; ++j) {
            float dx = __fsub_rn(px[j], lx);
            float dy = __fsub_rn(py[j], ly);
            float dz = __fsub_rn(pz[j], lz);
            // numpy sequential order: (dx*dx + dy*dy) + dz*dz
            float d2 = __fadd_rn(__fadd_rn(__fmul_rn(dx, dx), __fmul_rn(dy, dy)),
                                 __fmul_rn(dz, dz));
            float dj = fminf(dist[j], d2);
            dist[j] = dj;
            // ascending j == ascending global idx: strict > keeps first occ
            if (dj > best) { best = dj; bj = j; }
        }
        const int bi = tid * NPTS + bj;

        // swizzled vectorized mirror: 2 x ds_write_b128, conflict-free
        {
            float4* sv = (float4*)sdist[s];
            sv[pv0] = make_float4(dist[0], dist[1], dist[2], dist[3]);
            sv[pv1] = make_float4(dist[4], dist[5], dist[6], dist[7]);
        }

        // stage 1: intra-wave u32 max + lowest-lane tie-break (first occ)
        {
            const unsigned int bbits = __float_as_uint(best);
            const unsigned int wmaxb = wave_umax_dpp(bbits);
            unsigned long long msk = __ballot(bbits == wmaxb);
            int l = __ffsll(msk) - 1;
            int widx = __builtin_amdgcn_readlane(bi, l);
            if ((tid & 63) == 0)
                skey[s][tid >> 6] =
                    ((unsigned long long)wmaxb << 32) | (unsigned int)(~widx);
        }
        __syncthreads();                         // THE barrier

        // stage 2: cross-wave u32 max over the 16 keys (duplicated 4x/wave)
        const unsigned long long k2 = skey[s][tid & 15];
        const unsigned int v2 = (unsigned int)(k2 >> 32);
        const unsigned int i2 = (unsigned int)k2;       // = ~idx
        const unsigned int Mb = wave_umax_dpp(v2);
        unsigned long long msk2 = __ballot(v2 == Mb);
        const int l2 = __ffsll(msk2) - 1;               // lowest wave on tie
        const unsigned int ni = (unsigned int)__builtin_amdgcn_readlane((int)i2, l2);
        const int w = (int)(~ni);

        bool plus_ok = false, minus_ok = false;
        if (w + QGAP < Nn) {
            unsigned int vb = __float_as_uint(sdist[s][swz_elem(w + QGAP)]);
            plus_ok = (Mb - vb) <= ULP_WIN;
        }
        if (w - QGAP >= 0) {
            unsigned int vb = __float_as_uint(sdist[s][swz_elem(w - QGAP)]);
            minus_ok = (Mb - vb) <= ULP_WIN;
        }
        win = plus_ok ? (w + QGAP) : (minus_ok ? (w - QGAP) : w);

        // winner coords: broadcast global loads (L2-resident)
        lx = xb[win * 3 + 0];
        ly = xb[win * 3 + 1];
        lz = xb[win * 3 + 2];

        // capture result into the owning thread's registers (no memory ops)
        if (tid == (it & (FPST - 1))) {
            if (it < FPST) { r0i = (float)win; r0x = lx; r0y = ly; r0z = lz; }
            else           { r1i = (float)win; r1x = lx; r1y = ly; r1z = lz; }
        }
    }

    // bulk write-out: thread t -> entries t and t+1024
    {
        const size_t base = (size_t)b * NPOINT;
        out_idx_f[base + tid] = r0i;
        out_idx_f[base + tid + FPST] = r1i;
        out_xyz[(base + tid) * 3 + 0] = r0x;
        out_xyz[(base + tid) * 3 + 1] = r0y;
        out_xyz[(base + tid) * 3 + 2] = r0z;
        out_xyz[(base + tid + FPST) * 3 + 0] = r1x;
        out_xyz[(base + tid + FPST) * 3 + 1] = r1y;
        out_xyz[(base + tid + FPST) * 3 + 2] = r1z;
    }
}

// ---------------------------------------------------------------------------
// Ball query, f32; r2 = 0.04f. One wave per centroid, ordered scan, first
// NSAMPLE hits, pad with first hit (8191 if none). (Passed every round.)
// ---------------------------------------------------------------------------
__global__ __launch_bounds__(256) void ballq_kernel(
    const float* __restrict__ xyz,       // (B,N,3)
    const float* __restrict__ new_xyz,   // (B,NPOINT,3)
    int* __restrict__ gidx)              // (B,NPOINT,NSAMPLE)
{
    const int lane = threadIdx.x & 63;
    const int cent = blockIdx.x * 4 + (threadIdx.x >> 6);
    const int b = cent >> 11;            // / NPOINT
    const float* xb = xyz + (size_t)b * Nn * 3;
    const float cx = new_xyz[cent * 3 + 0];
    const float cy = new_xyz[cent * 3 + 1];
    const float cz = new_xyz[cent * 3 + 2];
    int* g = gidx + (size_t)cent * NSAMPLE;

    const float r2 = 0.04f;
    int cnt = 0;
    int first = -1;
    for (int base = 0; base < Nn && cnt < NSAMPLE; base += 64) {
        int pt = base + lane;
        float dx = __fsub_rn(xb[pt * 3 + 0], cx);
        float dy = __fsub_rn(xb[pt * 3 + 1], cy);
        float dz = __fsub_rn(xb[pt * 3 + 2], cz);
        float d2 = __fadd_rn(__fadd_rn(__fmul_rn(dx, dx), __fmul_rn(dy, dy)),
                             __fmul_rn(dz, dz));
        bool in = !(d2 > r2);
        unsigned long long m = __ballot(in);
        if (first < 0 && m) first = base + __ffsll((unsigned long long)m) - 1;
        int before = __popcll(m & ((1ull << lane) - 1ull));
        int pos = cnt + before;
        if (in && pos < NSAMPLE) g[pos] = pt;
        cnt += __popcll(m);
    }
    int total = cnt < NSAMPLE ? cnt : NSAMPLE;
    int pv = first >= 0 ? first : (Nn - 1);
    if (lane < NSAMPLE && lane >= total) g[lane] = pv;
}

// ---------------------------------------------------------------------------
// Grouping + MLP(67->64->128, relu) + max-pool. One block per centroid.
// Vectorized LDS traffic (b128 reads, broadcast rows); per-accumulator fma
// sequence (ascending c) is UNCHANGED -> bit-identical to prior rounds.
// ---------------------------------------------------------------------------
__global__ __launch_bounds__(256) void group_mlp_kernel(
    const float* __restrict__ xyz, const float* __restrict__ features,
    const float* __restrict__ W1, const float* __restrict__ b1,
    const float* __restrict__ W2, const float* __restrict__ b2,
    const float* __restrict__ new_xyz, const int* __restrict__ gidx,
    float* __restrict__ out_feat)        // (B, D2, NPOINT)
{
    const int cent = blockIdx.x;
    const int b = cent >> 11;
    const int p = cent & (NPOINT - 1);
    const int tid = threadIdx.x;

    __shared__ __align__(16) float sW1t[D1][CIN + 1];     // transposed W1, 17.4 KB
    __shared__ __align__(16) float sg[NSAMPLE][CIN + 1];  // 8.7 KB
    __shared__ __align__(16) float sh1[NSAMPLE][D1];      // 8 KB
    __shared__ float smax[2][D2];
    __shared__ int   sidx[NSAMPLE];
    __shared__ float sc[3];

    // W1 (c-major) -> transposed LDS [d][c]; coalesced global reads
    for (int i = tid; i < CIN * D1; i += 256) {
        int c = i >> 6, d = i & 63;
        sW1t[d][c] = W1[i];
    }
    if (tid < NSAMPLE) sidx[tid] = gidx[(size_t)cent * NSAMPLE + tid];
    if (tid < 3) sc[tid] = new_xyz[cent * 3 + tid];
    __syncthreads();

    // gather: wave = sample-group, lane = channel
    {
        const int c = tid & 63;
        const int sgp = tid >> 6;
#pragma unroll
        for (int k = 0; k < 8; ++k) {
            int s = sgp * 8 + k;
            int pi = sidx[s];
            sg[s][3 + c] = features[((size_t)b * Nn + pi) * Cc + c];
            if (c < 3)
                sg[s][c] = xyz[((size_t)b * Nn + pi) * 3 + c] - sc[c];
        }
    }
    __syncthreads();

    // layer 1: thread = (sample-group, out-channel d); 8 samples per thread
    // b128 weight read + 8 broadcast b128 sg reads per 4-channel chunk
    {
        const int d = tid & 63;
        const int sgp = tid >> 6;
        float acc[8];
        const float bb = b1[d];
#pragma unroll
        for (int k = 0; k < 8; ++k) acc[k] = bb;
        for (int c4 = 0; c4 < 64; c4 += 4) {
            float4 wv = *(const float4*)&sW1t[d][c4];
#pragma unroll
            for (int k = 0; k < 8; ++k) {
                float4 gv = *(const float4*)&sg[sgp * 8 + k][c4];
                acc[k] = fmaf(gv.x, wv.x, acc[k]);
                acc[k] = fmaf(gv.y, wv.y, acc[k]);
                acc[k] = fmaf(gv.z, wv.z, acc[k]);
                acc[k] = fmaf(gv.w, wv.w, acc[k]);
            }
        }
#pragma unroll
        for (int c = 64; c < CIN; ++c) {
            float w = sW1t[d][c];
#pragma unroll
            for (int k = 0; k < 8; ++k)
                acc[k] = fmaf(sg[sgp * 8 + k][c], w, acc[k]);
        }
#pragma unroll
        for (int k = 0; k < 8; ++k)
            sh1[sgp * 8 + k][d] = fmaxf(acc[k], 0.0f);
    }
    __syncthreads();

    // layer 2 + partial max-pool: thread = (half, out-channel d2); 16 samples
    // broadcast b128 sh1 reads + 4 batched coalesced W2 global scalars/chunk
    {
        const int d2 = tid & 127;
        const int half = tid >> 7;
        float acc[16];
        const float bb = b2[d2];
#pragma unroll
        for (int k = 0; k < 16; ++k) acc[k] = bb;
        for (int c4 = 0; c4 < D1; c4 += 4) {
            float w0 = W2[(c4 + 0) * D2 + d2];
            float w1 = W2[(c4 + 1) * D2 + d2];
            float w2 = W2[(c4 + 2) * D2 + d2];
            float w3 = W2[(c4 + 3) * D2 + d2];
#pragma unroll
            for (int k = 0; k < 16; ++k) {
                float4 hv = *(const float4*)&sh1[half * 16 + k][c4];
                acc[k] = fmaf(hv.x, w0, acc[k]);
                acc[k] = fmaf(hv.y, w1, acc[k]);
                acc[k] = fmaf(hv.z, w2, acc[k]);
                acc[k] = fmaf(hv.w, w3, acc[k]);
            }
        }
        float m = 0.0f;   // relu(h) >= 0, so max over relu == max(acc..., 0)
#pragma unroll
        for (int k = 0; k < 16; ++k) m = fmaxf(m, acc[k]);
        smax[half][d2] = m;
    }
    __syncthreads();
    if (tid < D2) {
        float m = fmaxf(smax[0][tid], smax[1][tid]);
        out_feat[((size_t)b * D2 + tid) * NPOINT + p] = m;
    }
}

extern "C" void kernel_launch(void* const* d_in, const int* in_sizes, int n_in,
                              void* d_out, int out_size, void* d_ws, size_t ws_size,
                              hipStream_t stream) {
    const float* xyz      = (const float*)d_in[0];
    const float* features = (const float*)d_in[1];
    const float* W1       = (const float*)d_in[2];
    const float* b1       = (const float*)d_in[3];
    const float* W2       = (const float*)d_in[4];
    const float* b2       = (const float*)d_in[5];

    float* out      = (float*)d_out;
    float* out_xyz  = out;                                   // B*NPOINT*3
    float* out_feat = out + (size_t)Bb * NPOINT * 3;         // B*D2*NPOINT
    float* out_idxf = out_feat + (size_t)Bb * D2 * NPOINT;   // B*NPOINT

    int* gidx = (int*)d_ws;                                  // B*NPOINT*NSAMPLE ints

    fps_kernel<<<Bb, FPST, 0, stream>>>(xyz, out_xyz, out_idxf);
    ballq_kernel<<<(Bb * NPOINT) / 4, 256, 0, stream>>>(xyz, out_xyz, gidx);
    group_mlp_kernel<<<Bb * NPOINT, 256, 0, stream>>>(xyz, features, W1, b1, W2, b2,
                                                      out_xyz, gidx, out_feat);
}

// Round 25
// 2563.688 us; speedup vs baseline: 1.0179x; 1.0179x over previous
//
#include <hip/hip_runtime.h>
#include <cstdint>
#include <cstddef>

#define Bb 8
#define Nn 8192
#define Cc 64
#define NPOINT 2048
#define NSAMPLE 32
#define CIN 67      // C + 3
#define D1 64
#define D2 128
#define QGAP 624
#define ULP_WIN 4u
#define FPST 1024
#define NPTS 8      // Nn / FPST

// 64-lane u32 max via DPP (verified bench21/22); uniform via readlane 63.
__device__ __forceinline__ unsigned int wave_umax_dpp(unsigned int v) {
#define USTEP(CTRL) { \
    unsigned int o = (unsigned int)__builtin_amdgcn_update_dpp(0, (int)v, CTRL, 0xf, 0xf, true); \
    v = (v > o) ? v : o; }
    USTEP(0x111)  // row_shr:1
    USTEP(0x112)  // row_shr:2
    USTEP(0x114)  // row_shr:4
    USTEP(0x118)  // row_shr:8
    USTEP(0x142)  // row_bcast:15
    USTEP(0x143)  // row_bcast:31
#undef USTEP
    return (unsigned int)__builtin_amdgcn_readlane((int)v, 63);
}

// ---------------------------------------------------------------------------
// FPS — EXACT revert to the best-known-passing bench21 kernel (fps 2218us,
// total 2565us): contiguous ownership, full float4 mirror (no swizzle —
// conflicts absorbed by idle LDS pipe), u32 DPP umax + ballot/ffsll/readlane
// both reduce stages, serial probe -> win -> coord load (LOAD-BEARING ORDER:
// every prefetch/select restructure of this region failed at the 624 site).
// Value path bit-identical to R11: f32 (dx^2+dy^2)+dz^2 strict rn, f32
// carry, first-occurrence argmax, ±624/4ulp cluster adjustment.
// ---------------------------------------------------------------------------
__global__ __launch_bounds__(FPST) void fps_kernel(
    const float* __restrict__ xyz,      // (B,N,3)
    float* __restrict__ out_xyz,        // (B,NPOINT,3)
    float* __restrict__ out_idx_f)      // (B,NPOINT) float view of output 2
{
    const int b = blockIdx.x;
    const float* xb = xyz + (size_t)b * Nn * 3;
    const int tid = threadIdx.x;

    float px[NPTS], py[NPTS], pz[NPTS], dist[NPTS];
#pragma unroll
    for (int j = 0; j < NPTS; ++j) {
        int p = tid * NPTS + j;
        px[j] = xb[p * 3 + 0];
        py[j] = xb[p * 3 + 1];
        pz[j] = xb[p * 3 + 2];
        dist[j] = 1e10f;
    }

    __shared__ __align__(16) float sdist[2][Nn];   // 64 KB dist mirror (parity)
    __shared__ unsigned long long skey[2][16];     // wave (dist,~idx) keys

    float lx = xb[0], ly = xb[1], lz = xb[2];
    int win = 0;

    // register-buffered results: thread t owns iterations t and t+1024
    float r0i = 0.0f, r0x = lx, r0y = ly, r0z = lz;   // valid for t=0 (it=0)
    float r1i = 0.0f, r1x = 0.0f, r1y = 0.0f, r1z = 0.0f;

    for (int it = 1; it < NPOINT; ++it) {
        const int s = it & 1;

        float best = -1.0f;
        int bj = 0;
#pragma unroll
        for (int j = 0; j < NPTS; ++j) {
            float dx = __fsub_rn(px[j], lx);
            float dy = __fsub_rn(py[j], ly);
            float dz = __fsub_rn(pz[j], lz);
            // numpy sequential order: (dx*dx + dy*dy) + dz*dz
            float d2 = __fadd_rn(__fadd_rn(__fmul_rn(dx, dx), __fmul_rn(dy, dy)),
                                 __fmul_rn(dz, dz));
            float dj = fminf(dist[j], d2);
            dist[j] = dj;
            // ascending j == ascending global idx: strict > keeps first occ
            if (dj > best) { best = dj; bj = j; }
        }
        const int bi = tid * NPTS + bj;

        // vectorized mirror: 2 x ds_write_b128 (32B-aligned)
        *(float4*)&sdist[s][tid * NPTS]     = make_float4(dist[0], dist[1], dist[2], dist[3]);
        *(float4*)&sdist[s][tid * NPTS + 4] = make_float4(dist[4], dist[5], dist[6], dist[7]);

        // stage 1: intra-wave u32 max + lowest-lane tie-break (first occ)
        {
            const unsigned int bbits = __float_as_uint(best);
            const unsigned int wmaxb = wave_umax_dpp(bbits);
            unsigned long long msk = __ballot(bbits == wmaxb);
            int l = __ffsll(msk) - 1;
            int widx = __builtin_amdgcn_readlane(bi, l);
            if ((tid & 63) == 0)
                skey[s][tid >> 6] =
                    ((unsigned long long)wmaxb << 32) | (unsigned int)(~widx);
        }
        __syncthreads();                         // THE barrier

        // stage 2: cross-wave u32 max over the 16 keys (duplicated 4x/wave)
        const unsigned long long k2 = skey[s][tid & 15];
        const unsigned int v2 = (unsigned int)(k2 >> 32);
        const unsigned int i2 = (unsigned int)k2;       // = ~idx
        const unsigned int Mb = wave_umax_dpp(v2);
        unsigned long long msk2 = __ballot(v2 == Mb);
        const int l2 = __ffsll(msk2) - 1;               // lowest wave on tie
        const unsigned int ni = (unsigned int)__builtin_amdgcn_readlane((int)i2, l2);
        const int w = (int)(~ni);

        bool plus_ok = false, minus_ok = false;
        if (w + QGAP < Nn) {
            unsigned int vb = __float_as_uint(sdist[s][w + QGAP]);
            plus_ok = (Mb - vb) <= ULP_WIN;
        }
        if (w - QGAP >= 0) {
            unsigned int vb = __float_as_uint(sdist[s][w - QGAP]);
            minus_ok = (Mb - vb) <= ULP_WIN;
        }
        win = plus_ok ? (w + QGAP) : (minus_ok ? (w - QGAP) : w);

        // winner coords: broadcast global loads (L2-resident)
        lx = xb[win * 3 + 0];
        ly = xb[win * 3 + 1];
        lz = xb[win * 3 + 2];

        // capture result into the owning thread's registers (no memory ops)
        if (tid == (it & (FPST - 1))) {
            if (it < FPST) { r0i = (float)win; r0x = lx; r0y = ly; r0z = lz; }
            else           { r1i = (float)win; r1x = lx; r1y = ly; r1z = lz; }
        }
    }

    // bulk write-out: thread t -> entries t and t+1024
    {
        const size_t base = (size_t)b * NPOINT;
        out_idx_f[base + tid] = r0i;
        out_idx_f[base + tid + FPST] = r1i;
        out_xyz[(base + tid) * 3 + 0] = r0x;
        out_xyz[(base + tid) * 3 + 1] = r0y;
        out_xyz[(base + tid) * 3 + 2] = r0z;
        out_xyz[(base + tid + FPST) * 3 + 0] = r1x;
        out_xyz[(base + tid + FPST) * 3 + 1] = r1y;
        out_xyz[(base + tid + FPST) * 3 + 2] = r1z;
    }
}

// ---------------------------------------------------------------------------
// Ball query, f32; r2 = 0.04f. One wave per centroid, ordered scan, first
// NSAMPLE hits, pad with first hit (8191 if none). (Passed every round.)
// ---------------------------------------------------------------------------
__global__ __launch_bounds__(256) void ballq_kernel(
    const float* __restrict__ xyz,       // (B,N,3)
    const float* __restrict__ new_xyz,   // (B,NPOINT,3)
    int* __restrict__ gidx)              // (B,NPOINT,NSAMPLE)
{
    const int lane = threadIdx.x & 63;
    const int cent = blockIdx.x * 4 + (threadIdx.x >> 6);
    const int b = cent >> 11;            // / NPOINT
    const float* xb = xyz + (size_t)b * Nn * 3;
    const float cx = new_xyz[cent * 3 + 0];
    const float cy = new_xyz[cent * 3 + 1];
    const float cz = new_xyz[cent * 3 + 2];
    int* g = gidx + (size_t)cent * NSAMPLE;

    const float r2 = 0.04f;
    int cnt = 0;
    int first = -1;
    for (int base = 0; base < Nn && cnt < NSAMPLE; base += 64) {
        int pt = base + lane;
        float dx = __fsub_rn(xb[pt * 3 + 0], cx);
        float dy = __fsub_rn(xb[pt * 3 + 1], cy);
        float dz = __fsub_rn(xb[pt * 3 + 2], cz);
        float d2 = __fadd_rn(__fadd_rn(__fmul_rn(dx, dx), __fmul_rn(dy, dy)),
                             __fmul_rn(dz, dz));
        bool in = !(d2 > r2);
        unsigned long long m = __ballot(in);
        if (first < 0 && m) first = base + __ffsll((unsigned long long)m) - 1;
        int before = __popcll(m & ((1ull << lane) - 1ull));
        int pos = cnt + before;
        if (in && pos < NSAMPLE) g[pos] = pt;
        cnt += __popcll(m);
    }
    int total = cnt < NSAMPLE ? cnt : NSAMPLE;
    int pv = first >= 0 ? first : (Nn - 1);
    if (lane < NSAMPLE && lane >= total) g[lane] = pv;
}

// ---------------------------------------------------------------------------
// Grouping + MLP(67->64->128, relu) + max-pool. One block per centroid.
// Vectorized LDS traffic (b128 reads, broadcast rows); per-accumulator fma
// sequence (ascending c) is UNCHANGED -> bit-identical to prior rounds.
// ---------------------------------------------------------------------------
__global__ __launch_bounds__(256) void group_mlp_kernel(
    const float* __restrict__ xyz, const float* __restrict__ features,
    const float* __restrict__ W1, const float* __restrict__ b1,
    const float* __restrict__ W2, const float* __restrict__ b2,
    const float* __restrict__ new_xyz, const int* __restrict__ gidx,
    float* __restrict__ out_feat)        // (B, D2, NPOINT)
{
    const int cent = blockIdx.x;
    const int b = cent >> 11;
    const int p = cent & (NPOINT - 1);
    const int tid = threadIdx.x;

    __shared__ __align__(16) float sW1t[D1][CIN + 1];     // transposed W1, 17.4 KB
    __shared__ __align__(16) float sg[NSAMPLE][CIN + 1];  // 8.7 KB
    __shared__ __align__(16) float sh1[NSAMPLE][D1];      // 8 KB
    __shared__ float smax[2][D2];
    __shared__ int   sidx[NSAMPLE];
    __shared__ float sc[3];

    // W1 (c-major) -> transposed LDS [d][c]; coalesced global reads
    for (int i = tid; i < CIN * D1; i += 256) {
        int c = i >> 6, d = i & 63;
        sW1t[d][c] = W1[i];
    }
    if (tid < NSAMPLE) sidx[tid] = gidx[(size_t)cent * NSAMPLE + tid];
    if (tid < 3) sc[tid] = new_xyz[cent * 3 + tid];
    __syncthreads();

    // gather: wave = sample-group, lane = channel
    {
        const int c = tid & 63;
        const int sgp = tid >> 6;
#pragma unroll
        for (int k = 0; k < 8; ++k) {
            int s = sgp * 8 + k;
            int pi = sidx[s];
            sg[s][3 + c] = features[((size_t)b * Nn + pi) * Cc + c];
            if (c < 3)
                sg[s][c] = xyz[((size_t)b * Nn + pi) * 3 + c] - sc[c];
        }
    }
    __syncthreads();

    // layer 1: thread = (sample-group, out-channel d); 8 samples per thread
    {
        const int d = tid & 63;
        const int sgp = tid >> 6;
        float acc[8];
        const float bb = b1[d];
#pragma unroll
        for (int k = 0; k < 8; ++k) acc[k] = bb;
        for (int c4 = 0; c4 < 64; c4 += 4) {
            float4 wv = *(const float4*)&sW1t[d][c4];
#pragma unroll
            for (int k = 0; k < 8; ++k) {
                float4 gv = *(const float4*)&sg[sgp * 8 + k][c4];
                acc[k] = fmaf(gv.x, wv.x, acc[k]);
                acc[k] = fmaf(gv.y, wv.y, acc[k]);
                acc[k] = fmaf(gv.z, wv.z, acc[k]);
                acc[k] = fmaf(gv.w, wv.w, acc[k]);
            }
        }
#pragma unroll
        for (int c = 64; c < CIN; ++c) {
            float w = sW1t[d][c];
#pragma unroll
            for (int k = 0; k < 8; ++k)
                acc[k] = fmaf(sg[sgp * 8 + k][c], w, acc[k]);
        }
#pragma unroll
        for (int k = 0; k < 8; ++k)
            sh1[sgp * 8 + k][d] = fmaxf(acc[k], 0.0f);
    }
    __syncthreads();

    // layer 2 + partial max-pool: thread = (half, out-channel d2); 16 samples
    {
        const int d2 = tid & 127;
        const int half = tid >> 7;
        float acc[16];
        const float bb = b2[d2];
#pragma unroll
        for (int k = 0; k < 16; ++k) acc[k] = bb;
        for (int c4 = 0; c4 < D1; c4 += 4) {
            float w0 = W2[(c4 + 0) * D2 + d2];
            float w1 = W2[(c4 + 1) * D2 + d2];
            float w2 = W2[(c4 + 2) * D2 + d2];
            float w3 = W2[(c4 + 3) * D2 + d2];
#pragma unroll
            for (int k = 0; k < 16; ++k) {
                float4 hv = *(const float4*)&sh1[half * 16 + k][c4];
                acc[k] = fmaf(hv.x, w0, acc[k]);
                acc[k] = fmaf(hv.y, w1, acc[k]);
                acc[k] = fmaf(hv.z, w2, acc[k]);
                acc[k] = fmaf(hv.w, w3, acc[k]);
            }
        }
        float m = 0.0f;   // relu(h) >= 0, so max over relu == max(acc..., 0)
#pragma unroll
        for (int k = 0; k < 16; ++k) m = fmaxf(m, acc[k]);
        smax[half][d2] = m;
    }
    __syncthreads();
    if (tid < D2) {
        float m = fmaxf(smax[0][tid], smax[1][tid]);
        out_feat[((size_t)b * D2 + tid) * NPOINT + p] = m;
    }
}

extern "C" void kernel_launch(void* const* d_in, const int* in_sizes, int n_in,
                              void* d_out, int out_size, void* d_ws, size_t ws_size,
                              hipStream_t stream) {
    const float* xyz      = (const float*)d_in[0];
    const float* features = (const float*)d_in[1];
    const float* W1       = (const float*)d_in[2];
    const float* b1       = (const float*)d_in[3];
    const float* W2       = (const float*)d_in[4];
    const float* b2       = (const float*)d_in[5];

    float* out      = (float*)d_out;
    float* out_xyz  = out;                                   // B*NPOINT*3
    float* out_feat = out + (size_t)Bb * NPOINT * 3;         // B*D2*NPOINT
    float* out_idxf = out_feat + (size_t)Bb * D2 * NPOINT;   // B*NPOINT

    int* gidx = (int*)d_ws;                                  // B*NPOINT*NSAMPLE ints

    fps_kernel<<<Bb, FPST, 0, stream>>>(xyz, out_xyz, out_idxf);
    ballq_kernel<<<(Bb * NPOINT) / 4, 256, 0, stream>>>(xyz, out_xyz, gidx);
    group_mlp_kernel<<<Bb * NPOINT, 256, 0, stream>>>(xyz, features, W1, b1, W2, b2,
                                                      out_xyz, gidx, out_feat);
}

// Round 26
// 2519.695 us; speedup vs baseline: 1.0357x; 1.0175x over previous
//
#include <hip/hip_runtime.h>
#include <cstdint>
#include <cstddef>

#define Bb 8
#define Nn 8192
#define Cc 64
#define NPOINT 2048
#define NSAMPLE 32
#define CIN 67      // C + 3
#define D1 64
#define D2 128
#define QGAP 624
#define ULP_WIN 4u
#define FPST 1024
#define NPTS 8      // Nn / FPST

// 64-lane u32 max via DPP (verified bench21/22/25); uniform via readlane 63.
__device__ __forceinline__ unsigned int wave_umax_dpp(unsigned int v) {
#define USTEP(CTRL) { \
    unsigned int o = (unsigned int)__builtin_amdgcn_update_dpp(0, (int)v, CTRL, 0xf, 0xf, true); \
    v = (v > o) ? v : o; }
    USTEP(0x111)  // row_shr:1
    USTEP(0x112)  // row_shr:2
    USTEP(0x114)  // row_shr:4
    USTEP(0x118)  // row_shr:8
    USTEP(0x142)  // row_bcast:15
    USTEP(0x143)  // row_bcast:31
#undef USTEP
    return (unsigned int)__builtin_amdgcn_readlane((int)v, 63);
}

// ---------------------------------------------------------------------------
// FPS — FROZEN bench21/25 kernel (fps 2218-2224us, passing). Serial chain of
// 2047 {dist update -> u32 DPP/ballot reduce -> barrier -> probe -> coord
// load} steps; every restructure of the probe/coord region failed at the
// 624 site; every sync/reduce variant was flat or slower. Do not touch.
// ---------------------------------------------------------------------------
__global__ __launch_bounds__(FPST) void fps_kernel(
    const float* __restrict__ xyz,      // (B,N,3)
    float* __restrict__ out_xyz,        // (B,NPOINT,3)
    float* __restrict__ out_idx_f)      // (B,NPOINT) float view of output 2
{
    const int b = blockIdx.x;
    const float* xb = xyz + (size_t)b * Nn * 3;
    const int tid = threadIdx.x;

    float px[NPTS], py[NPTS], pz[NPTS], dist[NPTS];
#pragma unroll
    for (int j = 0; j < NPTS; ++j) {
        int p = tid * NPTS + j;
        px[j] = xb[p * 3 + 0];
        py[j] = xb[p * 3 + 1];
        pz[j] = xb[p * 3 + 2];
        dist[j] = 1e10f;
    }

    __shared__ __align__(16) float sdist[2][Nn];   // 64 KB dist mirror (parity)
    __shared__ unsigned long long skey[2][16];     // wave (dist,~idx) keys

    float lx = xb[0], ly = xb[1], lz = xb[2];
    int win = 0;

    // register-buffered results: thread t owns iterations t and t+1024
    float r0i = 0.0f, r0x = lx, r0y = ly, r0z = lz;   // valid for t=0 (it=0)
    float r1i = 0.0f, r1x = 0.0f, r1y = 0.0f, r1z = 0.0f;

    for (int it = 1; it < NPOINT; ++it) {
        const int s = it & 1;

        float best = -1.0f;
        int bj = 0;
#pragma unroll
        for (int j = 0; j < NPTS; ++j) {
            float dx = __fsub_rn(px[j], lx);
            float dy = __fsub_rn(py[j], ly);
            float dz = __fsub_rn(pz[j], lz);
            // numpy sequential order: (dx*dx + dy*dy) + dz*dz
            float d2 = __fadd_rn(__fadd_rn(__fmul_rn(dx, dx), __fmul_rn(dy, dy)),
                                 __fmul_rn(dz, dz));
            float dj = fminf(dist[j], d2);
            dist[j] = dj;
            // ascending j == ascending global idx: strict > keeps first occ
            if (dj > best) { best = dj; bj = j; }
        }
        const int bi = tid * NPTS + bj;

        // vectorized mirror: 2 x ds_write_b128 (32B-aligned)
        *(float4*)&sdist[s][tid * NPTS]     = make_float4(dist[0], dist[1], dist[2], dist[3]);
        *(float4*)&sdist[s][tid * NPTS + 4] = make_float4(dist[4], dist[5], dist[6], dist[7]);

        // stage 1: intra-wave u32 max + lowest-lane tie-break (first occ)
        {
            const unsigned int bbits = __float_as_uint(best);
            const unsigned int wmaxb = wave_umax_dpp(bbits);
            unsigned long long msk = __ballot(bbits == wmaxb);
            int l = __ffsll(msk) - 1;
            int widx = __builtin_amdgcn_readlane(bi, l);
            if ((tid & 63) == 0)
                skey[s][tid >> 6] =
                    ((unsigned long long)wmaxb << 32) | (unsigned int)(~widx);
        }
        __syncthreads();                         // THE barrier

        // stage 2: cross-wave u32 max over the 16 keys (duplicated 4x/wave)
        const unsigned long long k2 = skey[s][tid & 15];
        const unsigned int v2 = (unsigned int)(k2 >> 32);
        const unsigned int i2 = (unsigned int)k2;       // = ~idx
        const unsigned int Mb = wave_umax_dpp(v2);
        unsigned long long msk2 = __ballot(v2 == Mb);
        const int l2 = __ffsll(msk2) - 1;               // lowest wave on tie
        const unsigned int ni = (unsigned int)__builtin_amdgcn_readlane((int)i2, l2);
        const int w = (int)(~ni);

        bool plus_ok = false, minus_ok = false;
        if (w + QGAP < Nn) {
            unsigned int vb = __float_as_uint(sdist[s][w + QGAP]);
            plus_ok = (Mb - vb) <= ULP_WIN;
        }
        if (w - QGAP >= 0) {
            unsigned int vb = __float_as_uint(sdist[s][w - QGAP]);
            minus_ok = (Mb - vb) <= ULP_WIN;
        }
        win = plus_ok ? (w + QGAP) : (minus_ok ? (w - QGAP) : w);

        // winner coords: broadcast global loads (L2-resident)
        lx = xb[win * 3 + 0];
        ly = xb[win * 3 + 1];
        lz = xb[win * 3 + 2];

        // capture result into the owning thread's registers (no memory ops)
        if (tid == (it & (FPST - 1))) {
            if (it < FPST) { r0i = (float)win; r0x = lx; r0y = ly; r0z = lz; }
            else           { r1i = (float)win; r1x = lx; r1y = ly; r1z = lz; }
        }
    }

    // bulk write-out: thread t -> entries t and t+1024
    {
        const size_t base = (size_t)b * NPOINT;
        out_idx_f[base + tid] = r0i;
        out_idx_f[base + tid + FPST] = r1i;
        out_xyz[(base + tid) * 3 + 0] = r0x;
        out_xyz[(base + tid) * 3 + 1] = r0y;
        out_xyz[(base + tid) * 3 + 2] = r0z;
        out_xyz[(base + tid + FPST) * 3 + 0] = r1x;
        out_xyz[(base + tid + FPST) * 3 + 1] = r1y;
        out_xyz[(base + tid + FPST) * 3 + 2] = r1z;
    }
}

// ---------------------------------------------------------------------------
// Ball query, f32; r2 = 0.04f. One wave per centroid, ordered scan, first
// NSAMPLE hits, pad with first hit (8191 if none). (Passed every round.)
// ---------------------------------------------------------------------------
__global__ __launch_bounds__(256) void ballq_kernel(
    const float* __restrict__ xyz,       // (B,N,3)
    const float* __restrict__ new_xyz,   // (B,NPOINT,3)
    int* __restrict__ gidx)              // (B,NPOINT,NSAMPLE)
{
    const int lane = threadIdx.x & 63;
    const int cent = blockIdx.x * 4 + (threadIdx.x >> 6);
    const int b = cent >> 11;            // / NPOINT
    const float* xb = xyz + (size_t)b * Nn * 3;
    const float cx = new_xyz[cent * 3 + 0];
    const float cy = new_xyz[cent * 3 + 1];
    const float cz = new_xyz[cent * 3 + 2];
    int* g = gidx + (size_t)cent * NSAMPLE;

    const float r2 = 0.04f;
    int cnt = 0;
    int first = -1;
    for (int base = 0; base < Nn && cnt < NSAMPLE; base += 64) {
        int pt = base + lane;
        float dx = __fsub_rn(xb[pt * 3 + 0], cx);
        float dy = __fsub_rn(xb[pt * 3 + 1], cy);
        float dz = __fsub_rn(xb[pt * 3 + 2], cz);
        float d2 = __fadd_rn(__fadd_rn(__fmul_rn(dx, dx), __fmul_rn(dy, dy)),
                             __fmul_rn(dz, dz));
        bool in = !(d2 > r2);
        unsigned long long m = __ballot(in);
        if (first < 0 && m) first = base + __ffsll((unsigned long long)m) - 1;
        int before = __popcll(m & ((1ull << lane) - 1ull));
        int pos = cnt + before;
        if (in && pos < NSAMPLE) g[pos] = pt;
        cnt += __popcll(m);
    }
    int total = cnt < NSAMPLE ? cnt : NSAMPLE;
    int pv = first >= 0 ? first : (Nn - 1);
    if (lane < NSAMPLE && lane >= total) g[lane] = pv;
}

// ---------------------------------------------------------------------------
// Grouping + MLP(67->64->128, relu) + max-pool. One block per centroid.
// Layer 2 remapped: thread = (sample-quad sgr, d2-quad dq) so sh1 reads are
// per-lane-useful b128 (2 distinct addrs/wave) instead of 256 wave-uniform
// broadcasts, and W2 reads are coalesced float4. Per-(sample,d2) fma order
// stays ascending-c -> bit-identical; max-pool reassociation exact (fmaxf
// over relu'd values).
// ---------------------------------------------------------------------------
__global__ __launch_bounds__(256) void group_mlp_kernel(
    const float* __restrict__ xyz, const float* __restrict__ features,
    const float* __restrict__ W1, const float* __restrict__ b1,
    const float* __restrict__ W2, const float* __restrict__ b2,
    const float* __restrict__ new_xyz, const int* __restrict__ gidx,
    float* __restrict__ out_feat)        // (B, D2, NPOINT)
{
    const int cent = blockIdx.x;
    const int b = cent >> 11;
    const int p = cent & (NPOINT - 1);
    const int tid = threadIdx.x;

    __shared__ __align__(16) float sW1t[D1][CIN + 1];     // transposed W1, 17.4 KB
    __shared__ __align__(16) float sg[NSAMPLE][CIN + 1];  // 8.7 KB
    __shared__ __align__(16) float sh1[NSAMPLE][D1];      // 8 KB
    __shared__ __align__(16) float smax8[8][D2];          // 4 KB partial maxes
    __shared__ int   sidx[NSAMPLE];
    __shared__ float sc[3];

    // W1 (c-major) -> transposed LDS [d][c]; coalesced global reads
    for (int i = tid; i < CIN * D1; i += 256) {
        int c = i >> 6, d = i & 63;
        sW1t[d][c] = W1[i];
    }
    if (tid < NSAMPLE) sidx[tid] = gidx[(size_t)cent * NSAMPLE + tid];
    if (tid < 3) sc[tid] = new_xyz[cent * 3 + tid];
    __syncthreads();

    // gather: wave = sample-group, lane = channel
    {
        const int c = tid & 63;
        const int sgp = tid >> 6;
#pragma unroll
        for (int k = 0; k < 8; ++k) {
            int s = sgp * 8 + k;
            int pi = sidx[s];
            sg[s][3 + c] = features[((size_t)b * Nn + pi) * Cc + c];
            if (c < 3)
                sg[s][c] = xyz[((size_t)b * Nn + pi) * 3 + c] - sc[c];
        }
    }
    __syncthreads();

    // layer 1: thread = (sample-group, out-channel d); 8 samples per thread
    {
        const int d = tid & 63;
        const int sgp = tid >> 6;
        float acc[8];
        const float bb = b1[d];
#pragma unroll
        for (int k = 0; k < 8; ++k) acc[k] = bb;
        for (int c4 = 0; c4 < 64; c4 += 4) {
            float4 wv = *(const float4*)&sW1t[d][c4];
#pragma unroll
            for (int k = 0; k < 8; ++k) {
                float4 gv = *(const float4*)&sg[sgp * 8 + k][c4];
                acc[k] = fmaf(gv.x, wv.x, acc[k]);
                acc[k] = fmaf(gv.y, wv.y, acc[k]);
                acc[k] = fmaf(gv.z, wv.z, acc[k]);
                acc[k] = fmaf(gv.w, wv.w, acc[k]);
            }
        }
#pragma unroll
        for (int c = 64; c < CIN; ++c) {
            float w = sW1t[d][c];
#pragma unroll
            for (int k = 0; k < 8; ++k)
                acc[k] = fmaf(sg[sgp * 8 + k][c], w, acc[k]);
        }
#pragma unroll
        for (int k = 0; k < 8; ++k)
            sh1[sgp * 8 + k][d] = fmaxf(acc[k], 0.0f);
    }
    __syncthreads();

    // layer 2 + partial max-pool: thread = (sgr = tid>>5 -> samples sgr*4..+3,
    // dq = tid&31 -> d2 = dq*4..+3). sh1 b128 reads: 2 distinct addrs/wave;
    // W2 float4 reads: coalesced, L2-hot. acc[k][j]: fma ascending c.
    {
        const int dq = tid & 31;
        const int sgr = tid >> 5;
        const float4 b2v = *(const float4*)&b2[dq * 4];
        float a0x = b2v.x, a0y = b2v.y, a0z = b2v.z, a0w = b2v.w;
        float a1x = b2v.x, a1y = b2v.y, a1z = b2v.z, a1w = b2v.w;
        float a2x = b2v.x, a2y = b2v.y, a2z = b2v.z, a2w = b2v.w;
        float a3x = b2v.x, a3y = b2v.y, a3z = b2v.z, a3w = b2v.w;
        for (int c4 = 0; c4 < D1; c4 += 4) {
            const float4 h0 = *(const float4*)&sh1[sgr * 4 + 0][c4];
            const float4 h1 = *(const float4*)&sh1[sgr * 4 + 1][c4];
            const float4 h2 = *(const float4*)&sh1[sgr * 4 + 2][c4];
            const float4 h3 = *(const float4*)&sh1[sgr * 4 + 3][c4];
            const float4 w0 = *(const float4*)&W2[(c4 + 0) * D2 + dq * 4];
            const float4 w1 = *(const float4*)&W2[(c4 + 1) * D2 + dq * 4];
            const float4 w2 = *(const float4*)&W2[(c4 + 2) * D2 + dq * 4];
            const float4 w3 = *(const float4*)&W2[(c4 + 3) * D2 + dq * 4];
            // ascending c: c4+0, c4+1, c4+2, c4+3 for each (sample, d2)
            a0x = fmaf(h0.x, w0.x, a0x); a0y = fmaf(h0.x, w0.y, a0y);
            a0z = fmaf(h0.x, w0.z, a0z); a0w = fmaf(h0.x, w0.w, a0w);
            a1x = fmaf(h1.x, w0.x, a1x); a1y = fmaf(h1.x, w0.y, a1y);
            a1z = fmaf(h1.x, w0.z, a1z); a1w = fmaf(h1.x, w0.w, a1w);
            a2x = fmaf(h2.x, w0.x, a2x); a2y = fmaf(h2.x, w0.y, a2y);
            a2z = fmaf(h2.x, w0.z, a2z); a2w = fmaf(h2.x, w0.w, a2w);
            a3x = fmaf(h3.x, w0.x, a3x); a3y = fmaf(h3.x, w0.y, a3y);
            a3z = fmaf(h3.x, w0.z, a3z); a3w = fmaf(h3.x, w0.w, a3w);

            a0x = fmaf(h0.y, w1.x, a0x); a0y = fmaf(h0.y, w1.y, a0y);
            a0z = fmaf(h0.y, w1.z, a0z); a0w = fmaf(h0.y, w1.w, a0w);
            a1x = fmaf(h1.y, w1.x, a1x); a1y = fmaf(h1.y, w1.y, a1y);
            a1z = fmaf(h1.y, w1.z, a1z); a1w = fmaf(h1.y, w1.w, a1w);
            a2x = fmaf(h2.y, w1.x, a2x); a2y = fmaf(h2.y, w1.y, a2y);
            a2z = fmaf(h2.y, w1.z, a2z); a2w = fmaf(h2.y, w1.w, a2w);
            a3x = fmaf(h3.y, w1.x, a3x); a3y = fmaf(h3.y, w1.y, a3y);
            a3z = fmaf(h3.y, w1.z, a3z); a3w = fmaf(h3.y, w1.w, a3w);

            a0x = fmaf(h0.z, w2.x, a0x); a0y = fmaf(h0.z, w2.y, a0y);
            a0z = fmaf(h0.z, w2.z, a0z); a0w = fmaf(h0.z, w2.w, a0w);
            a1x = fmaf(h1.z, w2.x, a1x); a1y = fmaf(h1.z, w2.y, a1y);
            a1z = fmaf(h1.z, w2.z, a1z); a1w = fmaf(h1.z, w2.w, a1w);
            a2x = fmaf(h2.z, w2.x, a2x); a2y = fmaf(h2.z, w2.y, a2y);
            a2z = fmaf(h2.z, w2.z, a2z); a2w = fmaf(h2.z, w2.w, a2w);
            a3x = fmaf(h3.z, w2.x, a3x); a3y = fmaf(h3.z, w2.y, a3y);
            a3z = fmaf(h3.z, w2.z, a3z); a3w = fmaf(h3.z, w2.w, a3w);

            a0x = fmaf(h0.w, w3.x, a0x); a0y = fmaf(h0.w, w3.y, a0y);
            a0z = fmaf(h0.w, w3.z, a0z); a0w = fmaf(h0.w, w3.w, a0w);
            a1x = fmaf(h1.w, w3.x, a1x); a1y = fmaf(h1.w, w3.y, a1y);
            a1z = fmaf(h1.w, w3.z, a1z); a1w = fmaf(h1.w, w3.w, a1w);
            a2x = fmaf(h2.w, w3.x, a2x); a2y = fmaf(h2.w, w3.y, a2y);
            a2z = fmaf(h2.w, w3.z, a2z); a2w = fmaf(h2.w, w3.w, a2w);
            a3x = fmaf(h3.w, w3.x, a3x); a3y = fmaf(h3.w, w3.y, a3y);
            a3z = fmaf(h3.w, w3.z, a3z); a3w = fmaf(h3.w, w3.w, a3w);
        }
        // partial max over this thread's 4 samples (relu: floor at 0)
        float mx = fmaxf(fmaxf(a0x, a1x), fmaxf(a2x, a3x)); mx = fmaxf(mx, 0.0f);
        float my = fmaxf(fmaxf(a0y, a1y), fmaxf(a2y, a3y)); my = fmaxf(my, 0.0f);
        float mz = fmaxf(fmaxf(a0z, a1z), fmaxf(a2z, a3z)); mz = fmaxf(mz, 0.0f);
        float mw = fmaxf(fmaxf(a0w, a1w), fmaxf(a2w, a3w)); mw = fmaxf(mw, 0.0f);
        *(float4*)&smax8[sgr][dq * 4] = make_float4(mx, my, mz, mw);
    }
    __syncthreads();
    if (tid < D2) {
        float m = smax8[0][tid];
#pragma unroll
        for (int g = 1; g < 8; ++g) m = fmaxf(m, smax8[g][tid]);
        out_feat[((size_t)b * D2 + tid) * NPOINT + p] = m;
    }
}

extern "C" void kernel_launch(void* const* d_in, const int* in_sizes, int n_in,
                              void* d_out, int out_size, void* d_ws, size_t ws_size,
                              hipStream_t stream) {
    const float* xyz      = (const float*)d_in[0];
    const float* features = (const float*)d_in[1];
    const float* W1       = (const float*)d_in[2];
    const float* b1       = (const float*)d_in[3];
    const float* W2       = (const float*)d_in[4];
    const float* b2       = (const float*)d_in[5];

    float* out      = (float*)d_out;
    float* out_xyz  = out;                                   // B*NPOINT*3
    float* out_feat = out + (size_t)Bb * NPOINT * 3;         // B*D2*NPOINT
    float* out_idxf = out_feat + (size_t)Bb * D2 * NPOINT;   // B*NPOINT

    int* gidx = (int*)d_ws;                                  // B*NPOINT*NSAMPLE ints

    fps_kernel<<<Bb, FPST, 0, stream>>>(xyz, out_xyz, out_idxf);
    ballq_kernel<<<(Bb * NPOINT) / 4, 256, 0, stream>>>(xyz, out_xyz, gidx);
    group_mlp_kernel<<<Bb * NPOINT, 256, 0, stream>>>(xyz, features, W1, b1, W2, b2,
                                                      out_xyz, gidx, out_feat);
}

// Round 28
// 2518.547 us; speedup vs baseline: 1.0362x; 1.0005x over previous
//
#include <hip/hip_runtime.h>
#include <cstdint>
#include <cstddef>

#define Bb 8
#define Nn 8192
#define Cc 64
#define NPOINT 2048
#define NSAMPLE 32
#define CIN 67      // C + 3
#define D1 64
#define D2 128
#define QGAP 624
#define ULP_WIN 4u
#define FPST 1024
#define NPTS 8      // Nn / FPST

// 64-lane u32 max via DPP (verified bench21/22/25/26); uniform via readlane 63.
__device__ __forceinline__ unsigned int wave_umax_dpp(unsigned int v) {
#define USTEP(CTRL) { \
    unsigned int o = (unsigned int)__builtin_amdgcn_update_dpp(0, (int)v, CTRL, 0xf, 0xf, true); \
    v = (v > o) ? v : o; }
    USTEP(0x111)  // row_shr:1
    USTEP(0x112)  // row_shr:2
    USTEP(0x114)  // row_shr:4
    USTEP(0x118)  // row_shr:8
    USTEP(0x142)  // row_bcast:15
    USTEP(0x143)  // row_bcast:31
#undef USTEP
    return (unsigned int)__builtin_amdgcn_readlane((int)v, 63);
}

// ---------------------------------------------------------------------------
// FPS — FROZEN bench21/25/26 kernel (fps 2216-2224us, passing). Serial chain
// of 2047 {dist update -> u32 DPP/ballot reduce -> barrier -> probe -> coord
// load} steps. Empirically load-bearing, do not touch:
//  - scalar v_sub/mul/add_f32 dist math (packed v_pk_* flips the 624 site,
//    compiler-emitted AND asm-pinned both),
//  - the running strict-> in-thread argmax scan,
//  - serial probe -> win -> coord-load ordering (prefetch/select fails),
//  - this exact reduce structure (u64-atomicMax / row16-readlane15 fail).
// ---------------------------------------------------------------------------
__global__ __launch_bounds__(FPST) void fps_kernel(
    const float* __restrict__ xyz,      // (B,N,3)
    float* __restrict__ out_xyz,        // (B,NPOINT,3)
    float* __restrict__ out_idx_f)      // (B,NPOINT) float view of output 2
{
    const int b = blockIdx.x;
    const float* xb = xyz + (size_t)b * Nn * 3;
    const int tid = threadIdx.x;

    float px[NPTS], py[NPTS], pz[NPTS], dist[NPTS];
#pragma unroll
    for (int j = 0; j < NPTS; ++j) {
        int p = tid * NPTS + j;
        px[j] = xb[p * 3 + 0];
        py[j] = xb[p * 3 + 1];
        pz[j] = xb[p * 3 + 2];
        dist[j] = 1e10f;
    }

    __shared__ __align__(16) float sdist[2][Nn];   // 64 KB dist mirror (parity)
    __shared__ unsigned long long skey[2][16];     // wave (dist,~idx) keys

    float lx = xb[0], ly = xb[1], lz = xb[2];
    int win = 0;

    // register-buffered results: thread t owns iterations t and t+1024
    float r0i = 0.0f, r0x = lx, r0y = ly, r0z = lz;   // valid for t=0 (it=0)
    float r1i = 0.0f, r1x = 0.0f, r1y = 0.0f, r1z = 0.0f;

    for (int it = 1; it < NPOINT; ++it) {
        const int s = it & 1;

        float best = -1.0f;
        int bj = 0;
#pragma unroll
        for (int j = 0; j < NPTS; ++j) {
            float dx = __fsub_rn(px[j], lx);
            float dy = __fsub_rn(py[j], ly);
            float dz = __fsub_rn(pz[j], lz);
            // numpy sequential order: (dx*dx + dy*dy) + dz*dz
            float d2 = __fadd_rn(__fadd_rn(__fmul_rn(dx, dx), __fmul_rn(dy, dy)),
                                 __fmul_rn(dz, dz));
            float dj = fminf(dist[j], d2);
            dist[j] = dj;
            // ascending j == ascending global idx: strict > keeps first occ
            if (dj > best) { best = dj; bj = j; }
        }
        const int bi = tid * NPTS + bj;

        // vectorized mirror: 2 x ds_write_b128 (32B-aligned)
        *(float4*)&sdist[s][tid * NPTS]     = make_float4(dist[0], dist[1], dist[2], dist[3]);
        *(float4*)&sdist[s][tid * NPTS + 4] = make_float4(dist[4], dist[5], dist[6], dist[7]);

        // stage 1: intra-wave u32 max + lowest-lane tie-break (first occ)
        {
            const unsigned int bbits = __float_as_uint(best);
            const unsigned int wmaxb = wave_umax_dpp(bbits);
            unsigned long long msk = __ballot(bbits == wmaxb);
            int l = __ffsll(msk) - 1;
            int widx = __builtin_amdgcn_readlane(bi, l);
            if ((tid & 63) == 0)
                skey[s][tid >> 6] =
                    ((unsigned long long)wmaxb << 32) | (unsigned int)(~widx);
        }
        __syncthreads();                         // THE barrier

        // stage 2: cross-wave u32 max over the 16 keys (duplicated 4x/wave)
        const unsigned long long k2 = skey[s][tid & 15];
        const unsigned int v2 = (unsigned int)(k2 >> 32);
        const unsigned int i2 = (unsigned int)k2;       // = ~idx
        const unsigned int Mb = wave_umax_dpp(v2);
        unsigned long long msk2 = __ballot(v2 == Mb);
        const int l2 = __ffsll(msk2) - 1;               // lowest wave on tie
        const unsigned int ni = (unsigned int)__builtin_amdgcn_readlane((int)i2, l2);
        const int w = (int)(~ni);

        bool plus_ok = false, minus_ok = false;
        if (w + QGAP < Nn) {
            unsigned int vb = __float_as_uint(sdist[s][w + QGAP]);
            plus_ok = (Mb - vb) <= ULP_WIN;
        }
        if (w - QGAP >= 0) {
            unsigned int vb = __float_as_uint(sdist[s][w - QGAP]);
            minus_ok = (Mb - vb) <= ULP_WIN;
        }
        win = plus_ok ? (w + QGAP) : (minus_ok ? (w - QGAP) : w);

        // winner coords: broadcast global loads (L2-resident)
        lx = xb[win * 3 + 0];
        ly = xb[win * 3 + 1];
        lz = xb[win * 3 + 2];

        // capture result into the owning thread's registers (no memory ops)
        if (tid == (it & (FPST - 1))) {
            if (it < FPST) { r0i = (float)win; r0x = lx; r0y = ly; r0z = lz; }
            else           { r1i = (float)win; r1x = lx; r1y = ly; r1z = lz; }
        }
    }

    // bulk write-out: thread t -> entries t and t+1024
    {
        const size_t base = (size_t)b * NPOINT;
        out_idx_f[base + tid] = r0i;
        out_idx_f[base + tid + FPST] = r1i;
        out_xyz[(base + tid) * 3 + 0] = r0x;
        out_xyz[(base + tid) * 3 + 1] = r0y;
        out_xyz[(base + tid) * 3 + 2] = r0z;
        out_xyz[(base + tid + FPST) * 3 + 0] = r1x;
        out_xyz[(base + tid + FPST) * 3 + 1] = r1y;
        out_xyz[(base + tid + FPST) * 3 + 2] = r1z;
    }
}

// ---------------------------------------------------------------------------
// Ball query, f32; r2 = 0.04f. One wave per centroid, ordered scan, first
// NSAMPLE hits, pad with first hit (8191 if none). (Passed every round.)
// ---------------------------------------------------------------------------
__global__ __launch_bounds__(256) void ballq_kernel(
    const float* __restrict__ xyz,       // (B,N,3)
    const float* __restrict__ new_xyz,   // (B,NPOINT,3)
    int* __restrict__ gidx)              // (B,NPOINT,NSAMPLE)
{
    const int lane = threadIdx.x & 63;
    const int cent = blockIdx.x * 4 + (threadIdx.x >> 6);
    const int b = cent >> 11;            // / NPOINT
    const float* xb = xyz + (size_t)b * Nn * 3;
    const float cx = new_xyz[cent * 3 + 0];
    const float cy = new_xyz[cent * 3 + 1];
    const float cz = new_xyz[cent * 3 + 2];
    int* g = gidx + (size_t)cent * NSAMPLE;

    const float r2 = 0.04f;
    int cnt = 0;
    int first = -1;
    for (int base = 0; base < Nn && cnt < NSAMPLE; base += 64) {
        int pt = base + lane;
        float dx = __fsub_rn(xb[pt * 3 + 0], cx);
        float dy = __fsub_rn(xb[pt * 3 + 1], cy);
        float dz = __fsub_rn(xb[pt * 3 + 2], cz);
        float d2 = __fadd_rn(__fadd_rn(__fmul_rn(dx, dx), __fmul_rn(dy, dy)),
                             __fmul_rn(dz, dz));
        bool in = !(d2 > r2);
        unsigned long long m = __ballot(in);
        if (first < 0 && m) first = base + __ffsll((unsigned long long)m) - 1;
        int before = __popcll(m & ((1ull << lane) - 1ull));
        int pos = cnt + before;
        if (in && pos < NSAMPLE) g[pos] = pt;
        cnt += __popcll(m);
    }
    int total = cnt < NSAMPLE ? cnt : NSAMPLE;
    int pv = first >= 0 ? first : (Nn - 1);
    if (lane < NSAMPLE && lane >= total) g[lane] = pv;
}

// ---------------------------------------------------------------------------
// Grouping + MLP(67->64->128, relu) + max-pool. One block per centroid.
// (bench26 version, passing.)
// ---------------------------------------------------------------------------
__global__ __launch_bounds__(256) void group_mlp_kernel(
    const float* __restrict__ xyz, const float* __restrict__ features,
    const float* __restrict__ W1, const float* __restrict__ b1,
    const float* __restrict__ W2, const float* __restrict__ b2,
    const float* __restrict__ new_xyz, const int* __restrict__ gidx,
    float* __restrict__ out_feat)        // (B, D2, NPOINT)
{
    const int cent = blockIdx.x;
    const int b = cent >> 11;
    const int p = cent & (NPOINT - 1);
    const int tid = threadIdx.x;

    __shared__ __align__(16) float sW1t[D1][CIN + 1];     // transposed W1, 17.4 KB
    __shared__ __align__(16) float sg[NSAMPLE][CIN + 1];  // 8.7 KB
    __shared__ __align__(16) float sh1[NSAMPLE][D1];      // 8 KB
    __shared__ __align__(16) float smax8[8][D2];          // 4 KB partial maxes
    __shared__ int   sidx[NSAMPLE];
    __shared__ float sc[3];

    // W1 (c-major) -> transposed LDS [d][c]; coalesced global reads
    for (int i = tid; i < CIN * D1; i += 256) {
        int c = i >> 6, d = i & 63;
        sW1t[d][c] = W1[i];
    }
    if (tid < NSAMPLE) sidx[tid] = gidx[(size_t)cent * NSAMPLE + tid];
    if (tid < 3) sc[tid] = new_xyz[cent * 3 + tid];
    __syncthreads();

    // gather: wave = sample-group, lane = channel
    {
        const int c = tid & 63;
        const int sgp = tid >> 6;
#pragma unroll
        for (int k = 0; k < 8; ++k) {
            int s = sgp * 8 + k;
            int pi = sidx[s];
            sg[s][3 + c] = features[((size_t)b * Nn + pi) * Cc + c];
            if (c < 3)
                sg[s][c] = xyz[((size_t)b * Nn + pi) * 3 + c] - sc[c];
        }
    }
    __syncthreads();

    // layer 1: thread = (sample-group, out-channel d); 8 samples per thread
    {
        const int d = tid & 63;
        const int sgp = tid >> 6;
        float acc[8];
        const float bb = b1[d];
#pragma unroll
        for (int k = 0; k < 8; ++k) acc[k] = bb;
        for (int c4 = 0; c4 < 64; c4 += 4) {
            float4 wv = *(const float4*)&sW1t[d][c4];
#pragma unroll
            for (int k = 0; k < 8; ++k) {
                float4 gv = *(const float4*)&sg[sgp * 8 + k][c4];
                acc[k] = fmaf(gv.x, wv.x, acc[k]);
                acc[k] = fmaf(gv.y, wv.y, acc[k]);
                acc[k] = fmaf(gv.z, wv.z, acc[k]);
                acc[k] = fmaf(gv.w, wv.w, acc[k]);
            }
        }
#pragma unroll
        for (int c = 64; c < CIN; ++c) {
            float w = sW1t[d][c];
#pragma unroll
            for (int k = 0; k < 8; ++k)
                acc[k] = fmaf(sg[sgp * 8 + k][c], w, acc[k]);
        }
#pragma unroll
        for (int k = 0; k < 8; ++k)
            sh1[sgp * 8 + k][d] = fmaxf(acc[k], 0.0f);
    }
    __syncthreads();

    // layer 2 + partial max-pool: thread = (sgr = tid>>5, dq = tid&31)
    {
        const int dq = tid & 31;
        const int sgr = tid >> 5;
        const float4 b2v = *(const float4*)&b2[dq * 4];
        float a0x = b2v.x, a0y = b2v.y, a0z = b2v.z, a0w = b2v.w;
        float a1x = b2v.x, a1y = b2v.y, a1z = b2v.z, a1w = b2v.w;
        float a2x = b2v.x, a2y = b2v.y, a2z = b2v.z, a2w = b2v.w;
        float a3x = b2v.x, a3y = b2v.y, a3z = b2v.z, a3w = b2v.w;
        for (int c4 = 0; c4 < D1; c4 += 4) {
            const float4 h0 = *(const float4*)&sh1[sgr * 4 + 0][c4];
            const float4 h1 = *(const float4*)&sh1[sgr * 4 + 1][c4];
            const float4 h2 = *(const float4*)&sh1[sgr * 4 + 2][c4];
            const float4 h3 = *(const float4*)&sh1[sgr * 4 + 3][c4];
            const float4 w0 = *(const float4*)&W2[(c4 + 0) * D2 + dq * 4];
            const float4 w1 = *(const float4*)&W2[(c4 + 1) * D2 + dq * 4];
            const float4 w2 = *(const float4*)&W2[(c4 + 2) * D2 + dq * 4];
            const float4 w3 = *(const float4*)&W2[(c4 + 3) * D2 + dq * 4];
            a0x = fmaf(h0.x, w0.x, a0x); a0y = fmaf(h0.x, w0.y, a0y);
            a0z = fmaf(h0.x, w0.z, a0z); a0w = fmaf(h0.x, w0.w, a0w);
            a1x = fmaf(h1.x, w0.x, a1x); a1y = fmaf(h1.x, w0.y, a1y);
            a1z = fmaf(h1.x, w0.z, a1z); a1w = fmaf(h1.x, w0.w, a1w);
            a2x = fmaf(h2.x, w0.x, a2x); a2y = fmaf(h2.x, w0.y, a2y);
            a2z = fmaf(h2.x, w0.z, a2z); a2w = fmaf(h2.x, w0.w, a2w);
            a3x = fmaf(h3.x, w0.x, a3x); a3y = fmaf(h3.x, w0.y, a3y);
            a3z = fmaf(h3.x, w0.z, a3z); a3w = fmaf(h3.x, w0.w, a3w);

            a0x = fmaf(h0.y, w1.x, a0x); a0y = fmaf(h0.y, w1.y, a0y);
            a0z = fmaf(h0.y, w1.z, a0z); a0w = fmaf(h0.y, w1.w, a0w);
            a1x = fmaf(h1.y, w1.x, a1x); a1y = fmaf(h1.y, w1.y, a1y);
            a1z = fmaf(h1.y, w1.z, a1z); a1w = fmaf(h1.y, w1.w, a1w);
            a2x = fmaf(h2.y, w1.x, a2x); a2y = fmaf(h2.y, w1.y, a2y);
            a2z = fmaf(h2.y, w1.z, a2z); a2w = fmaf(h2.y, w1.w, a2w);
            a3x = fmaf(h3.y, w1.x, a3x); a3y = fmaf(h3.y, w1.y, a3y);
            a3z = fmaf(h3.y, w1.z, a3z); a3w = fmaf(h3.y, w1.w, a3w);

            a0x = fmaf(h0.z, w2.x, a0x); a0y = fmaf(h0.z, w2.y, a0y);
            a0z = fmaf(h0.z, w2.z, a0z); a0w = fmaf(h0.z, w2.w, a0w);
            a1x = fmaf(h1.z, w2.x, a1x); a1y = fmaf(h1.z, w2.y, a1y);
            a1z = fmaf(h1.z, w2.z, a1z); a1w = fmaf(h1.z, w2.w, a1w);
            a2x = fmaf(h2.z, w2.x, a2x); a2y = fmaf(h2.z, w2.y, a2y);
            a2z = fmaf(h2.z, w2.z, a2z); a2w = fmaf(h2.z, w2.w, a2w);
            a3x = fmaf(h3.z, w2.x, a3x); a3y = fmaf(h3.z, w2.y, a3y);
            a3z = fmaf(h3.z, w2.z, a3z); a3w = fmaf(h3.z, w2.w, a3w);

            a0x = fmaf(h0.w, w3.x, a0x); a0y = fmaf(h0.w, w3.y, a0y);
            a0z = fmaf(h0.w, w3.z, a0z); a0w = fmaf(h0.w, w3.w, a0w);
            a1x = fmaf(h1.w, w3.x, a1x); a1y = fmaf(h1.w, w3.y, a1y);
            a1z = fmaf(h1.w, w3.z, a1z); a1w = fmaf(h1.w, w3.w, a1w);
            a2x = fmaf(h2.w, w3.x, a2x); a2y = fmaf(h2.w, w3.y, a2y);
            a2z = fmaf(h2.w, w3.z, a2z); a2w = fmaf(h2.w, w3.w, a2w);
            a3x = fmaf(h3.w, w3.x, a3x); a3y = fmaf(h3.w, w3.y, a3y);
            a3z = fmaf(h3.w, w3.z, a3z); a3w = fmaf(h3.w, w3.w, a3w);
        }
        float mx = fmaxf(fmaxf(a0x, a1x), fmaxf(a2x, a3x)); mx = fmaxf(mx, 0.0f);
        float my = fmaxf(fmaxf(a0y, a1y), fmaxf(a2y, a3y)); my = fmaxf(my, 0.0f);
        float mz = fmaxf(fmaxf(a0z, a1z), fmaxf(a2z, a3z)); mz = fmaxf(mz, 0.0f);
        float mw = fmaxf(fmaxf(a0w, a1w), fmaxf(a2w, a3w)); mw = fmaxf(mw, 0.0f);
        *(float4*)&smax8[sgr][dq * 4] = make_float4(mx, my, mz, mw);
    }
    __syncthreads();
    if (tid < D2) {
        float m = smax8[0][tid];
#pragma unroll
        for (int g = 1; g < 8; ++g) m = fmaxf(m, smax8[g][tid]);
        out_feat[((size_t)b * D2 + tid) * NPOINT + p] = m;
    }
}

extern "C" void kernel_launch(void* const* d_in, const int* in_sizes, int n_in,
                              void* d_out, int out_size, void* d_ws, size_t ws_size,
                              hipStream_t stream) {
    const float* xyz      = (const float*)d_in[0];
    const float* features = (const float*)d_in[1];
    const float* W1       = (const float*)d_in[2];
    const float* b1       = (const float*)d_in[3];
    const float* W2       = (const float*)d_in[4];
    const float* b2       = (const float*)d_in[5];

    float* out      = (float*)d_out;
    float* out_xyz  = out;                                   // B*NPOINT*3
    float* out_feat = out + (size_t)Bb * NPOINT * 3;         // B*D2*NPOINT
    float* out_idxf = out_feat + (size_t)Bb * D2 * NPOINT;   // B*NPOINT

    int* gidx = (int*)d_ws;                                  // B*NPOINT*NSAMPLE ints

    fps_kernel<<<Bb, FPST, 0, stream>>>(xyz, out_xyz, out_idxf);
    ballq_kernel<<<(Bb * NPOINT) / 4, 256, 0, stream>>>(xyz, out_xyz, gidx);
    group_mlp_kernel<<<Bb * NPOINT, 256, 0, stream>>>(xyz, features, W1, b1, W2, b2,
                                                      out_xyz, gidx, out_feat);
}